// Round 6
// baseline (9553.275 us; speedup 1.0000x reference)
//
#include <hip/hip_runtime.h>

typedef __attribute__((ext_vector_type(8))) short short8;
typedef __attribute__((ext_vector_type(4))) float floatx4;

#define BQ 16
#define LQ 512
#define DM 1024
#define DPROJ 4384
#define RAWC 2336
#define KD 2048
#define NWG 128          // scan workgroups
#define NTHR 512         // threads per scan wg (8 waves)
#define AWG 73           // wgs running phase A: 73 x 32 cols = 2336

__device__ __forceinline__ float siluf(float x) { return x / (1.f + __expf(-x)); }
__device__ __forceinline__ float softplusf(float x) { return (x > 20.f) ? x : log1pf(__expf(x)); }
__device__ __forceinline__ unsigned short f2bf(float f) {
    union { float f; unsigned u; } v; v.f = f;
    unsigned r = v.u + 0x7FFFu + ((v.u >> 16) & 1u);
    return (unsigned short)(r >> 16);
}

// ---------------- fp32 -> bf16 conversion ----------------
__global__ void cvt_bf16_kernel(const float* __restrict__ s, unsigned short* __restrict__ d, int n) {
    int i = blockIdx.x * 256 + threadIdx.x;
    if (i < n) d[i] = f2bf(s[i]);
}

// ---------------- pack [W_rxbc|W_rdt|W_out] -> bf16 [3360][2048] ----------------
__global__ void pack_weights_kernel(const float* __restrict__ rxbc, const float* __restrict__ rdt,
                                    const float* __restrict__ wout, unsigned short* __restrict__ wall) {
    long i = (long)blockIdx.x * 256 + threadIdx.x;
    if (i >= 3360L * KD) return;
    int c = (int)(i >> 11), k = (int)(i & 2047);
    const float* src = (c < 2304) ? rxbc + (long)c * KD + k
                     : (c < 2336) ? rdt + (long)(c - 2304) * KD + k
                     :              wout + (long)(c - 2336) * KD + k;
    wall[i] = f2bf(*src);
}

// ---------------- in_proj GEMM: (8192x1024)*(1024x4384) bf16 MFMA ----------------
__global__ __launch_bounds__(256) void gemm_inproj_kernel(const short* __restrict__ A,
                                                          const short* __restrict__ Bw,
                                                          float* __restrict__ C) {
    const int lane = threadIdx.x & 63, wave = threadIdx.x >> 6;
    const int row = lane & 15, q = lane >> 4;
    const long m0 = (long)blockIdx.x * 64 + wave * 16;
    const long n0 = (long)blockIdx.y * 32;
    const short* ap  = A  + (m0 + row) * DM + q * 8;
    const short* bp0 = Bw + (n0 + row) * DM + q * 8;
    const short* bp1 = bp0 + 16 * DM;
    floatx4 acc0 = {0.f,0.f,0.f,0.f}, acc1 = {0.f,0.f,0.f,0.f};
    for (int k = 0; k < DM; k += 32) {
        short8 a  = *(const short8*)(ap + k);
        short8 b0 = *(const short8*)(bp0 + k);
        short8 b1 = *(const short8*)(bp1 + k);
        acc0 = __builtin_amdgcn_mfma_f32_16x16x32_bf16(a, b0, acc0, 0, 0, 0);
        acc1 = __builtin_amdgcn_mfma_f32_16x16x32_bf16(a, b1, acc1, 0, 0, 0);
    }
    float* cp = C + (m0 + q * 4) * DPROJ + n0 + row;
    #pragma unroll
    for (int r = 0; r < 4; ++r) {
        cp[(long)r * DPROJ]      = acc0[r];
        cp[(long)r * DPROJ + 16] = acc1[r];
    }
}

// ---------------- zero init: ghist slot 0 + msum + barrier ----------------
__global__ void setup_zero_kernel(unsigned* ghist, float* msum, unsigned* bar) {
    int i = blockIdx.x * 256 + threadIdx.x;
    if (i < 16384) ghist[i] = 0u;        // slot 0: 16x2048 bf16 = 16384 u32
    if (i < 512) msum[i] = 0.f;          // [2][16][16]
    if (i < 1024) bar[i] = 0u;           // master + 16 sub-counters
}

// ---------------- 2-level grid barrier (16 subs x 8 arrivals, relaxed agent) ----------
__device__ __forceinline__ void gbar(unsigned* bar, unsigned k) {
    __syncthreads();   // each wave drains its own vmcnt before s_barrier
    if (threadIdx.x == 0) {
        asm volatile("s_waitcnt vmcnt(0)" ::: "memory");
        unsigned* sub = bar + 32 + (blockIdx.x & 15) * 32;
        unsigned old = __hip_atomic_fetch_add(sub, 1u, __ATOMIC_RELAXED, __HIP_MEMORY_SCOPE_AGENT);
        if (old == k * 8u - 1u)
            __hip_atomic_fetch_add(bar, 1u, __ATOMIC_RELAXED, __HIP_MEMORY_SCOPE_AGENT);
        while (__hip_atomic_load(bar, __ATOMIC_RELAXED, __HIP_MEMORY_SCOPE_AGENT) < k * 16u) {}
    }
    __syncthreads();
}

// ---------------- cooperative sequential scan + fused out-projection ----------------
// 128 wgs x 512 thr. Cooperative kernel is the LAST node in the graph (no trailing
// kernels — the R4 trailing-GEMM topology is the suspected container killer).
// Phase A (wgs 0..72): 2 tiles x 16 cols of [W_rxbc|W_rdt], 8-way K-split, A = ghist[t].
// Phase B (all 128): wg -> (batch w>>3, heads (w&7)*4..+3), state s[64]/lane in regs,
//   conv-on-the-fly, yn -> ghist[t+1] + msum flag slots.
// Post-loop: out[b][t] = scale_hist[b][t] * (ghist[t+1] @ W_out^T), all 128 wgs.
__global__ __launch_bounds__(NTHR, 1) void scan_kernel(
    const float* __restrict__ zx,       // [16][512][4384]
    float* __restrict__ raw,            // [16][2336]  (agent-scope)
    unsigned short* __restrict__ ghist, // [513][16][2048] bf16 (agent-scope)
    float* __restrict__ msum,           // [2][16][16] flag slots (agent-scope)
    unsigned* __restrict__ bar,
    const short* __restrict__ wall,     // [3360][2048] bf16
    float* __restrict__ scale_hist,     // [16][512] (agent-scope)
    const float* __restrict__ dt_bias, const float* __restrict__ A_log,
    const float* __restrict__ D_param, const float* __restrict__ norm_w,
    const float* __restrict__ conv_w, const float* __restrict__ conv_b,
    float* __restrict__ out)            // [16][512][1024]
{
    const int w = blockIdx.x, tid = threadIdx.x;
    const int lane = tid & 63, wv = tid >> 6;

    __shared__ float redu[2][8][16][16];   // 16 KB
    __shared__ float bc_lds[2][128];
    __shared__ float ypart[4][64];
    __shared__ float gsum[4];

    // ---- Phase A config ----
    const bool doA = (w < AWG);
    const int colr = lane & 15, q = lane >> 4;
    const unsigned long long* gq = (const unsigned long long*)ghist;  // slot stride 8192 u64
    const int abase = colr * 512 + wv * 64 + q * 2;
    const short* wp0 = wall + ((long)((2 * w    ) * 16 + colr) * KD + wv * 256 + q * 8);
    const short* wp1 = wall + ((long)((2 * w + 1) * 16 + colr) * KD + wv * 256 + q * 8);
    const int r_tl = tid >> 8, r_idx = tid & 255, r_orow = r_idx >> 4, r_col = r_idx & 15;

    // ---- Phase B config ----
    const int b = w >> 3;
    const int h = (w & 7) * 4 + (wv >> 1);
    const int half = wv & 1;
    float s[64];
    #pragma unroll
    for (int i = 0; i < 64; ++i) s[i] = 0.f;
    const float Aneg = -__expf(A_log[h]);
    const float dtb  = dt_bias[h];
    const float Dp   = D_param[h];
    const float nw   = norm_w[h * 64 + lane];
    const int cx = h * 64 + lane;                  // x conv channel (= z col)
    const float4 cwx = *(const float4*)(conv_w + cx * 4);
    const float cbx = conv_b[cx];
    const int bcw = tid >> 7, bcn = tid & 127;     // bc staging slot (tid<256)
    const int cbc = 2048 + bcw * 128 + bcn;        // B/C conv channel
    float4 cwbc = {0.f,0.f,0.f,0.f}; float cbbc = 0.f;
    if (tid < 256) { cwbc = *(const float4*)(conv_w + cbc * 4); cbbc = conv_b[cbc]; }

    unsigned target = 0;
    for (int t = 0; ; ++t) {
        // ---- prefetch step-t streams (drained at bar1, consumed in Phase B) ----
        float px0 = 0.f, px1 = 0.f, px2 = 0.f, px3 = 0.f, pf_z = 0.f, pf_dz = 0.f;
        float pb0 = 0.f, pb1 = 0.f, pb2 = 0.f, pb3 = 0.f;
        if (t < LQ) {
            const long zr = ((long)b * LQ + t) * DPROJ;
            if (t >= 3) px0 = zx[zr - 3 * DPROJ + 2048 + cx];
            if (t >= 2) px1 = zx[zr - 2 * DPROJ + 2048 + cx];
            if (t >= 1) px2 = zx[zr - 1 * DPROJ + 2048 + cx];
            px3 = zx[zr + 2048 + cx];
            pf_z  = zx[zr + cx];
            pf_dz = zx[zr + 4352 + h];
            if (tid < 256) {
                if (t >= 3) pb0 = zx[zr - 3 * DPROJ + 2048 + cbc];
                if (t >= 2) pb1 = zx[zr - 2 * DPROJ + 2048 + cbc];
                if (t >= 1) pb2 = zx[zr - 1 * DPROJ + 2048 + cbc];
                pb3 = zx[zr + 2048 + cbc];
            }
        }
        // ---- msum (flag slots, parity of step t-1) + scale ----
        float rs = 0.f;
        if (doA) {
            const float* mp = msum + (((t + 1) & 1) * 16 + r_orow) * 16;
            float msv = 0.f;
            #pragma unroll
            for (int k = 0; k < 8; ++k)
                msv += __hip_atomic_load(mp + k, __ATOMIC_RELAXED, __HIP_MEMORY_SCOPE_AGENT);
            rs = rsqrtf(msv * (1.f / 2048.f) + 1e-5f);
        }
        if (w == 0 && r_tl == 0 && r_col == 0 && t >= 1)
            __hip_atomic_store(scale_hist + r_orow * LQ + (t - 1), rs,
                               __ATOMIC_RELAXED, __HIP_MEMORY_SCOPE_AGENT);
        if (t == LQ) break;

        // ---- Phase A matmul ----
        if (doA) {
            unsigned long long ar[16];
            const long gb0 = (long)t * 8192 + abase;
            #pragma unroll
            for (int ks = 0; ks < 8; ++ks) {
                ar[2 * ks]     = __hip_atomic_load(gq + gb0 + ks * 8,
                                 __ATOMIC_RELAXED, __HIP_MEMORY_SCOPE_AGENT);
                ar[2 * ks + 1] = __hip_atomic_load(gq + gb0 + ks * 8 + 1,
                                 __ATOMIC_RELAXED, __HIP_MEMORY_SCOPE_AGENT);
            }
            floatx4 acc0 = {0.f,0.f,0.f,0.f}, acc1 = {0.f,0.f,0.f,0.f};
            #pragma unroll
            for (int ks = 0; ks < 8; ++ks) {
                union { unsigned long long u[2]; short8 s8; } af;
                af.u[0] = ar[2 * ks]; af.u[1] = ar[2 * ks + 1];
                short8 b0 = *(const short8*)(wp0 + ks * 32);
                short8 b1 = *(const short8*)(wp1 + ks * 32);
                acc0 = __builtin_amdgcn_mfma_f32_16x16x32_bf16(af.s8, b0, acc0, 0, 0, 0);
                acc1 = __builtin_amdgcn_mfma_f32_16x16x32_bf16(af.s8, b1, acc1, 0, 0, 0);
            }
            #pragma unroll
            for (int r = 0; r < 4; ++r) {
                redu[0][wv][q * 4 + r][colr] = acc0[r];
                redu[1][wv][q * 4 + r][colr] = acc1[r];
            }
        }
        __syncthreads();
        if (doA) {
            float v = 0.f;
            #pragma unroll
            for (int kq = 0; kq < 8; ++kq) v += redu[r_tl][kq][r_orow][r_col];
            v *= rs;
            int gc = (2 * w + r_tl) * 16 + r_col;
            __hip_atomic_store(raw + r_orow * RAWC + gc, v,
                               __ATOMIC_RELAXED, __HIP_MEMORY_SCOPE_AGENT);
        }
        target += NWG; gbar(bar, target / NWG);

        // ---- Phase B ----
        float* rawb = raw + b * RAWC;
        float bcval = 0.f;
        if (tid < 256) bcval = __hip_atomic_load(rawb + 2048 + bcw * 128 + bcn,
                                                 __ATOMIC_RELAXED, __HIP_MEMORY_SCOPE_AGENT);
        float xr   = __hip_atomic_load(rawb + cx,       __ATOMIC_RELAXED, __HIP_MEMORY_SCOPE_AGENT);
        float dtrr = __hip_atomic_load(rawb + 2304 + h, __ATOMIC_RELAXED, __HIP_MEMORY_SCOPE_AGENT);
        if (tid < 256) {
            float pre = cbbc + pb0 * cwbc.x + pb1 * cwbc.y + pb2 * cwbc.z + pb3 * cwbc.w;
            bc_lds[bcw][bcn] = siluf(pre + bcval);
        }
        float xpre = cbx + px0 * cwx.x + px1 * cwx.y + px2 * cwx.z + px3 * cwx.w;
        float xv = siluf(xpre + xr);
        float dt = softplusf(siluf(pf_dz + dtrr) + dtb);
        float dA = __expf(dt * Aneg);
        float zg = siluf(pf_z);
        __syncthreads();

        float dtx = dt * xv, yac = 0.f;
        const floatx4* Bp = (const floatx4*)&bc_lds[0][half * 64];
        const floatx4* Cp = (const floatx4*)&bc_lds[1][half * 64];
        #pragma unroll
        for (int i = 0; i < 16; ++i) {
            floatx4 b4 = Bp[i], c4 = Cp[i];
            s[4*i+0] = s[4*i+0] * dA + dtx * b4.x; yac += s[4*i+0] * c4.x;
            s[4*i+1] = s[4*i+1] * dA + dtx * b4.y; yac += s[4*i+1] * c4.y;
            s[4*i+2] = s[4*i+2] * dA + dtx * b4.z; yac += s[4*i+2] * c4.z;
            s[4*i+3] = s[4*i+3] * dA + dtx * b4.w; yac += s[4*i+3] * c4.w;
        }
        if (half) ypart[wv >> 1][lane] = yac;
        __syncthreads();
        if (!half) {
            float y = yac + ypart[wv >> 1][lane] + Dp * xv;
            float g = y * zg;
            unsigned gb = (unsigned)f2bf(g * nw);
            unsigned up = __shfl_down(gb, 1);
            if (!(lane & 1))
                __hip_atomic_store((unsigned*)ghist + ((long)(t + 1) * 16384
                                   + ((b * KD + h * 64 + lane) >> 1)),
                                   gb | (up << 16), __ATOMIC_RELAXED, __HIP_MEMORY_SCOPE_AGENT);
            float sq = g * g;
            #pragma unroll
            for (int off = 32; off; off >>= 1) sq += __shfl_xor(sq, off, 64);
            if (lane == 0) gsum[wv >> 1] = sq;
        }
        __syncthreads();
        if (tid == 0) {
            float tot = gsum[0] + gsum[1] + gsum[2] + gsum[3];
            __hip_atomic_store(msum + ((t & 1) * 16 + b) * 16 + (w & 7), tot,
                               __ATOMIC_RELAXED, __HIP_MEMORY_SCOPE_AGENT);
        }
        target += NWG; gbar(bar, target / NWG);
    }

    // ======== post-loop: fused out-projection (all 128 wgs) ========
    target += NWG; gbar(bar, target / NWG);   // scale_hist + ghist all visible
    {
        const int vb = w * 2 + (tid >> 8);    // virtual 256-thread block: 0..255
        const int vt = tid & 255;
        const int vwv = vt >> 6, vlane = vt & 63;
        const int vcolr = vlane & 15, vq = vlane >> 4;   // vcolr = batch row of A
        for (int it = 0; it < 8; ++it) {
            const int idx = vb * 8 + it;       // 0..2047 = (t, n-block)
            const int tt = idx >> 2;
            const int n0 = (idx & 3) * 256 + vwv * 64;
            const long ab = (long)(tt + 1) * 8192 + vcolr * 512 + vq * 2;
            const short* bp = wall + ((long)(2336 + n0 + vcolr) * KD + vq * 8);
            floatx4 acc0 = {0.f,0.f,0.f,0.f}, acc1 = {0.f,0.f,0.f,0.f};
            floatx4 acc2 = {0.f,0.f,0.f,0.f}, acc3 = {0.f,0.f,0.f,0.f};
            #pragma unroll 4
            for (int kb = 0; kb < 64; ++kb) {
                unsigned long long a0 = __hip_atomic_load(gq + ab + kb * 8,
                                        __ATOMIC_RELAXED, __HIP_MEMORY_SCOPE_AGENT);
                unsigned long long a1 = __hip_atomic_load(gq + ab + kb * 8 + 1,
                                        __ATOMIC_RELAXED, __HIP_MEMORY_SCOPE_AGENT);
                union { unsigned long long u[2]; short8 s8; } af;
                af.u[0] = a0; af.u[1] = a1;
                const short* bk = bp + kb * 32;
                acc0 = __builtin_amdgcn_mfma_f32_16x16x32_bf16(af.s8, *(const short8*)(bk),           acc0, 0, 0, 0);
                acc1 = __builtin_amdgcn_mfma_f32_16x16x32_bf16(af.s8, *(const short8*)(bk + 16 * KD), acc1, 0, 0, 0);
                acc2 = __builtin_amdgcn_mfma_f32_16x16x32_bf16(af.s8, *(const short8*)(bk + 32 * KD), acc2, 0, 0, 0);
                acc3 = __builtin_amdgcn_mfma_f32_16x16x32_bf16(af.s8, *(const short8*)(bk + 48 * KD), acc3, 0, 0, 0);
            }
            #pragma unroll
            for (int r = 0; r < 4; ++r) {
                const int bb = vq * 4 + r;     // batch
                float sc = __hip_atomic_load(scale_hist + bb * LQ + tt,
                                             __ATOMIC_RELAXED, __HIP_MEMORY_SCOPE_AGENT);
                float* op = out + ((long)bb * LQ + tt) * DM + n0 + vcolr;
                op[0]  = acc0[r] * sc;
                op[16] = acc1[r] * sc;
                op[32] = acc2[r] * sc;
                op[48] = acc3[r] * sc;
            }
        }
    }
}

extern "C" void kernel_launch(void* const* d_in, const int* in_sizes, int n_in,
                              void* d_out, int out_size, void* d_ws, size_t ws_size,
                              hipStream_t stream) {
    const float* u       = (const float*)d_in[0];
    const float* W_in    = (const float*)d_in[1];
    const float* conv_w  = (const float*)d_in[2];
    const float* conv_b  = (const float*)d_in[3];
    const float* W_rxbc  = (const float*)d_in[4];
    const float* W_rdt   = (const float*)d_in[5];
    const float* dt_bias = (const float*)d_in[6];
    const float* A_log   = (const float*)d_in[7];
    const float* D_param = (const float*)d_in[8];
    const float* norm_w  = (const float*)d_in[9];
    const float* W_out   = (const float*)d_in[10];
    float* out = (float*)d_out;

    char* ws = (char*)d_ws;
    size_t off = 0;
    auto alloc = [&](size_t bytes) -> void* {
        void* p = ws + off; off += (bytes + 255) & ~(size_t)255; return p;
    };
    float* zx            = (float*)alloc((size_t)BQ * LQ * DPROJ * 4);        // 143.7 MB
    unsigned short* u_bf = (unsigned short*)alloc((size_t)BQ * LQ * DM * 2);  // reused as wall
    unsigned short* w_bf = (unsigned short*)alloc((size_t)DPROJ * DM * 2);
    unsigned short* gh   = (unsigned short*)alloc((size_t)(LQ + 1) * BQ * KD * 2);  // 33.6 MB
    float* msum          = (float*)alloc(512 * 4);
    float* raw           = (float*)alloc((size_t)BQ * RAWC * 4);
    float* scale_hist    = (float*)alloc((size_t)BQ * LQ * 4);
    unsigned* bar        = (unsigned*)alloc(1024 * 4);

    { int n = BQ * LQ * DM; cvt_bf16_kernel<<<(n + 255) / 256, 256, 0, stream>>>(u, u_bf, n); }
    { int n = DPROJ * DM;   cvt_bf16_kernel<<<(n + 255) / 256, 256, 0, stream>>>(W_in, w_bf, n); }
    gemm_inproj_kernel<<<dim3(BQ * LQ / 64, DPROJ / 32), 256, 0, stream>>>(
        (const short*)u_bf, (const short*)w_bf, zx);
    unsigned short* wall = u_bf;   // dead after GEMM; reuse for packed scan weights
    { long n = 3360L * KD;
      pack_weights_kernel<<<(int)((n + 255) / 256), 256, 0, stream>>>(W_rxbc, W_rdt, W_out, wall); }
    setup_zero_kernel<<<64, 256, 0, stream>>>((unsigned*)gh, msum, bar);

    void* args[] = { &zx, &raw, &gh, &msum, &bar, &wall, &scale_hist,
                     &dt_bias, &A_log, &D_param, &norm_w, &conv_w, &conv_b, &out };
    hipLaunchCooperativeKernel((void*)scan_kernel, dim3(NWG), dim3(NTHR), args, 0, stream);
}

// Round 7
// 7598.268 us; speedup vs baseline: 1.2573x; 1.2573x over previous
//
#include <hip/hip_runtime.h>

typedef __attribute__((ext_vector_type(8))) short short8;
typedef __attribute__((ext_vector_type(4))) float floatx4;

#define BQ 16
#define LQ 512
#define DM 1024
#define DPROJ 4384
#define RAWC 2336
#define KD 2048
#define NWG 128          // scan workgroups
#define NTHR 512         // threads per scan wg (8 waves)
#define AWG 73           // wgs running phase A: 73 x 32 cols = 2336

__device__ __forceinline__ float siluf(float x) { return x / (1.f + __expf(-x)); }
__device__ __forceinline__ float softplusf(float x) { return (x > 20.f) ? x : log1pf(__expf(x)); }
__device__ __forceinline__ unsigned short f2bf(float f) {
    union { float f; unsigned u; } v; v.f = f;
    unsigned r = v.u + 0x7FFFu + ((v.u >> 16) & 1u);
    return (unsigned short)(r >> 16);
}

// ---------------- fp32 -> bf16 conversion ----------------
__global__ void cvt_bf16_kernel(const float* __restrict__ s, unsigned short* __restrict__ d, int n) {
    int i = blockIdx.x * 256 + threadIdx.x;
    if (i < n) d[i] = f2bf(s[i]);
}

// ---------------- pack [W_rxbc|W_rdt|W_out] -> bf16 [3360][2048] ----------------
__global__ void pack_weights_kernel(const float* __restrict__ rxbc, const float* __restrict__ rdt,
                                    const float* __restrict__ wout, unsigned short* __restrict__ wall) {
    long i = (long)blockIdx.x * 256 + threadIdx.x;
    if (i >= 3360L * KD) return;
    int c = (int)(i >> 11), k = (int)(i & 2047);
    const float* src = (c < 2304) ? rxbc + (long)c * KD + k
                     : (c < 2336) ? rdt + (long)(c - 2304) * KD + k
                     :              wout + (long)(c - 2336) * KD + k;
    wall[i] = f2bf(*src);
}

// ---------------- in_proj GEMM: 128x32 blocks (halves B re-reads vs 64x32) ----------
__global__ __launch_bounds__(256) void gemm_inproj_kernel(const short* __restrict__ A,
                                                          const short* __restrict__ Bw,
                                                          float* __restrict__ C) {
    const int lane = threadIdx.x & 63, wave = threadIdx.x >> 6;
    const int row = lane & 15, q = lane >> 4;
    const long m0 = (long)blockIdx.x * 128 + wave * 16;    // second m-tile at +64
    const long n0 = (long)blockIdx.y * 32;
    const short* ap0 = A + (m0 + row) * DM + q * 8;
    const short* ap1 = ap0 + 64 * DM;
    const short* bp0 = Bw + (n0 + row) * DM + q * 8;
    const short* bp1 = bp0 + 16 * DM;
    floatx4 acc00 = {0.f,0.f,0.f,0.f}, acc01 = {0.f,0.f,0.f,0.f};
    floatx4 acc10 = {0.f,0.f,0.f,0.f}, acc11 = {0.f,0.f,0.f,0.f};
    for (int k = 0; k < DM; k += 32) {
        short8 a0 = *(const short8*)(ap0 + k);
        short8 a1 = *(const short8*)(ap1 + k);
        short8 b0 = *(const short8*)(bp0 + k);
        short8 b1 = *(const short8*)(bp1 + k);
        acc00 = __builtin_amdgcn_mfma_f32_16x16x32_bf16(a0, b0, acc00, 0, 0, 0);
        acc01 = __builtin_amdgcn_mfma_f32_16x16x32_bf16(a0, b1, acc01, 0, 0, 0);
        acc10 = __builtin_amdgcn_mfma_f32_16x16x32_bf16(a1, b0, acc10, 0, 0, 0);
        acc11 = __builtin_amdgcn_mfma_f32_16x16x32_bf16(a1, b1, acc11, 0, 0, 0);
    }
    float* cp0 = C + (m0 + q * 4) * DPROJ + n0 + row;
    float* cp1 = cp0 + 64 * DPROJ;
    #pragma unroll
    for (int r = 0; r < 4; ++r) {
        cp0[(long)r * DPROJ]      = acc00[r];
        cp0[(long)r * DPROJ + 16] = acc01[r];
        cp1[(long)r * DPROJ]      = acc10[r];
        cp1[(long)r * DPROJ + 16] = acc11[r];
    }
}

// ---------------- zero init: ghist slot 0 + msum + flags ----------------
__global__ void setup_zero_kernel(unsigned* ghist, float* msum, unsigned* bar) {
    int i = blockIdx.x * 256 + threadIdx.x;
    if (i < 16384) ghist[i] = 0u;        // slot 0: 16x2048 bf16 = 16384 u32
    if (i < 512) msum[i] = 0.f;          // [2][16][16]
    if (i < 12288) bar[i] = 0u;          // bflag[0..4095], aflag[4096..8191], sflag[8192]
}

// ---------------- cooperative dataflow scan + fused out-projection ----------------
// NO grid barriers: epoch-tagged producer flags (drain -> flag store -> per-thread spin).
// A(t) waits bflag[*] >= t (128 flags, 1 thread each); computes raw[t&1] from ghist[t];
// posts aflag[w] = t+1. B(t) waits its 17 producer aflags >= t+1; computes state,
// ghist[t+1], msum(parity t); posts bflag[w] = t+1. Post-loop: out-projection GEMM.
__global__ __launch_bounds__(NTHR, 1) void scan_kernel(
    const float* __restrict__ zx,       // [16][512][4384]
    float* __restrict__ raw,            // [2][16][2336]  (agent-scope, parity)
    unsigned short* __restrict__ ghist, // [513][16][2048] bf16 (agent-scope)
    float* __restrict__ msum,           // [2][16][16] flag slots (agent-scope)
    unsigned* __restrict__ bar,         // flags
    const short* __restrict__ wall,     // [3360][2048] bf16
    float* __restrict__ scale_hist,     // [16][512] (agent-scope)
    const float* __restrict__ dt_bias, const float* __restrict__ A_log,
    const float* __restrict__ D_param, const float* __restrict__ norm_w,
    const float* __restrict__ conv_w, const float* __restrict__ conv_b,
    float* __restrict__ out)            // [16][512][1024]
{
    const int w = blockIdx.x, tid = threadIdx.x;
    const int lane = tid & 63, wv = tid >> 6;
    unsigned* bflag = bar;               // stride 32 u32 (one line per flag)
    unsigned* aflag = bar + 4096;
    unsigned* sflag = bar + 8192;

    __shared__ float redu[2][8][16][16];   // 16 KB
    __shared__ float bc_lds[2][128];
    __shared__ float ypart[4][64];
    __shared__ float gsum[4];

    // ---- Phase A config ----
    const bool doA = (w < AWG);
    const int colr = lane & 15, q = lane >> 4;
    const unsigned long long* gq = (const unsigned long long*)ghist;  // slot stride 8192 u64
    const int abase = colr * 512 + wv * 64 + q * 2;
    const short* wp0 = wall + ((long)((2 * w    ) * 16 + colr) * KD + wv * 256 + q * 8);
    const short* wp1 = wall + ((long)((2 * w + 1) * 16 + colr) * KD + wv * 256 + q * 8);
    const int r_tl = tid >> 8, r_idx = tid & 255, r_orow = r_idx >> 4, r_col = r_idx & 15;

    // ---- Phase B config ----
    const int b = w >> 3;
    const int j = w & 7;
    const int h = j * 4 + (wv >> 1);
    const int half = wv & 1;
    float s[64];
    #pragma unroll
    for (int i = 0; i < 64; ++i) s[i] = 0.f;
    const float Aneg = -__expf(A_log[h]);
    const float dtb  = dt_bias[h];
    const float Dp   = D_param[h];
    const float nw   = norm_w[h * 64 + lane];
    const int cx = h * 64 + lane;                  // x conv channel (= z col)
    const float4 cwx = *(const float4*)(conv_w + cx * 4);
    const float cbx = conv_b[cx];
    const int bcw = tid >> 7, bcn = tid & 127;     // bc staging slot (tid<256)
    const int cbc = 2048 + bcw * 128 + bcn;        // B/C conv channel
    float4 cwbc = {0.f,0.f,0.f,0.f}; float cbbc = 0.f;
    if (tid < 256) { cwbc = *(const float4*)(conv_w + cbc * 4); cbbc = conv_b[cbc]; }
    // rolling conv history registers (taps t-3..t-1); zero = left-pad
    float xh1 = 0.f, xh2 = 0.f, xh3 = 0.f, bh1 = 0.f, bh2 = 0.f, bh3 = 0.f;
    // B-side dependency flag index (17 producers: 8 x-tiles, 8 B/C, 1 dt)
    const unsigned depi = (tid < 8) ? (unsigned)(j * 8 + tid)
                        : (tid < 16) ? (unsigned)(64 + tid - 8) : 72u;

    for (int t = 0; ; ++t) {
        // ---- prefetch step-t streams (older than spin loads; drain overlaps spin) ----
        float xq = 0.f, zq = 0.f, dzq = 0.f, bq = 0.f;
        if (t < LQ) {
            const long zr = ((long)b * LQ + t) * DPROJ;
            xq  = zx[zr + 2048 + cx];
            zq  = zx[zr + cx];
            dzq = zx[zr + 4352 + h];
            if (tid < 256) bq = zx[zr + 2048 + cbc];
        }
        // ---- A-side: wait all B(t-1), then msum -> rs ----
        float rs = 0.f;
        if (doA) {
            if (tid < 128) {
                const unsigned* fp = bflag + tid * 32;
                while (__hip_atomic_load(fp, __ATOMIC_RELAXED, __HIP_MEMORY_SCOPE_AGENT)
                       < (unsigned)t) {}
            }
            __syncthreads();
            const float* mp = msum + (((t + 1) & 1) * 16 + r_orow) * 16;
            float msv = 0.f;
            #pragma unroll
            for (int k = 0; k < 8; ++k)
                msv += __hip_atomic_load(mp + k, __ATOMIC_RELAXED, __HIP_MEMORY_SCOPE_AGENT);
            rs = rsqrtf(msv * (1.f / 2048.f) + 1e-5f);
            if (w == 0 && r_tl == 0 && r_col == 0 && t >= 1)
                __hip_atomic_store(scale_hist + r_orow * LQ + (t - 1), rs,
                                   __ATOMIC_RELAXED, __HIP_MEMORY_SCOPE_AGENT);
        }
        if (t == LQ) {
            __syncthreads();
            if (w == 0 && tid == 0) {
                asm volatile("s_waitcnt vmcnt(0)" ::: "memory");
                __hip_atomic_store(sflag, 1u, __ATOMIC_RELAXED, __HIP_MEMORY_SCOPE_AGENT);
            }
            break;
        }
        // ---- Phase A matmul -> raw[t&1] -> post aflag ----
        if (doA) {
            unsigned long long ar[16];
            const long gb0 = (long)t * 8192 + abase;
            #pragma unroll
            for (int ks = 0; ks < 8; ++ks) {
                ar[2 * ks]     = __hip_atomic_load(gq + gb0 + ks * 8,
                                 __ATOMIC_RELAXED, __HIP_MEMORY_SCOPE_AGENT);
                ar[2 * ks + 1] = __hip_atomic_load(gq + gb0 + ks * 8 + 1,
                                 __ATOMIC_RELAXED, __HIP_MEMORY_SCOPE_AGENT);
            }
            floatx4 acc0 = {0.f,0.f,0.f,0.f}, acc1 = {0.f,0.f,0.f,0.f};
            #pragma unroll
            for (int ks = 0; ks < 8; ++ks) {
                union { unsigned long long u[2]; short8 s8; } af;
                af.u[0] = ar[2 * ks]; af.u[1] = ar[2 * ks + 1];
                short8 b0 = *(const short8*)(wp0 + ks * 32);
                short8 b1 = *(const short8*)(wp1 + ks * 32);
                acc0 = __builtin_amdgcn_mfma_f32_16x16x32_bf16(af.s8, b0, acc0, 0, 0, 0);
                acc1 = __builtin_amdgcn_mfma_f32_16x16x32_bf16(af.s8, b1, acc1, 0, 0, 0);
            }
            #pragma unroll
            for (int r = 0; r < 4; ++r) {
                redu[0][wv][q * 4 + r][colr] = acc0[r];
                redu[1][wv][q * 4 + r][colr] = acc1[r];
            }
            __syncthreads();
            float v = 0.f;
            #pragma unroll
            for (int kq = 0; kq < 8; ++kq) v += redu[r_tl][kq][r_orow][r_col];
            v *= rs;
            int gc = (2 * w + r_tl) * 16 + r_col;
            __hip_atomic_store(raw + (t & 1) * (16 * RAWC) + r_orow * RAWC + gc, v,
                               __ATOMIC_RELAXED, __HIP_MEMORY_SCOPE_AGENT);
            __syncthreads();   // all raw stores drained (per-wave vmcnt drain at barrier)
            if (tid == 0)
                __hip_atomic_store(aflag + w * 32, (unsigned)(t + 1),
                                   __ATOMIC_RELAXED, __HIP_MEMORY_SCOPE_AGENT);
        }
        // ---- B-side: wait the 17 producer A-wgs ----
        if (tid < 17) {
            const unsigned* fp = aflag + depi * 32;
            while (__hip_atomic_load(fp, __ATOMIC_RELAXED, __HIP_MEMORY_SCOPE_AGENT)
                   < (unsigned)(t + 1)) {}
        }
        __syncthreads();
        const float* rawb = raw + (t & 1) * (16 * RAWC) + b * RAWC;
        float bcval = 0.f;
        if (tid < 256) bcval = __hip_atomic_load(rawb + 2048 + bcw * 128 + bcn,
                                                 __ATOMIC_RELAXED, __HIP_MEMORY_SCOPE_AGENT);
        float xr   = __hip_atomic_load(rawb + cx,       __ATOMIC_RELAXED, __HIP_MEMORY_SCOPE_AGENT);
        float dtrr = __hip_atomic_load(rawb + 2304 + h, __ATOMIC_RELAXED, __HIP_MEMORY_SCOPE_AGENT);
        if (tid < 256) {
            float pre = cbbc + bh3 * cwbc.x + bh2 * cwbc.y + bh1 * cwbc.z + bq * cwbc.w;
            bc_lds[bcw][bcn] = siluf(pre + bcval);
            bh3 = bh2; bh2 = bh1; bh1 = bq;
        }
        float xpre = cbx + xh3 * cwx.x + xh2 * cwx.y + xh1 * cwx.z + xq * cwx.w;
        xh3 = xh2; xh2 = xh1; xh1 = xq;
        float xv = siluf(xpre + xr);
        float dt = softplusf(siluf(dzq + dtrr) + dtb);
        float dA = __expf(dt * Aneg);
        float zg = siluf(zq);
        __syncthreads();

        float dtx = dt * xv, yac = 0.f;
        const floatx4* Bp = (const floatx4*)&bc_lds[0][half * 64];
        const floatx4* Cp = (const floatx4*)&bc_lds[1][half * 64];
        #pragma unroll
        for (int i = 0; i < 16; ++i) {
            floatx4 b4 = Bp[i], c4 = Cp[i];
            s[4*i+0] = s[4*i+0] * dA + dtx * b4.x; yac += s[4*i+0] * c4.x;
            s[4*i+1] = s[4*i+1] * dA + dtx * b4.y; yac += s[4*i+1] * c4.y;
            s[4*i+2] = s[4*i+2] * dA + dtx * b4.z; yac += s[4*i+2] * c4.z;
            s[4*i+3] = s[4*i+3] * dA + dtx * b4.w; yac += s[4*i+3] * c4.w;
        }
        if (half) ypart[wv >> 1][lane] = yac;
        __syncthreads();
        if (!half) {
            float y = yac + ypart[wv >> 1][lane] + Dp * xv;
            float g = y * zg;
            unsigned gb = (unsigned)f2bf(g * nw);
            unsigned up = __shfl_down(gb, 1);
            if (!(lane & 1))
                __hip_atomic_store((unsigned*)ghist + ((long)(t + 1) * 16384
                                   + ((b * KD + h * 64 + lane) >> 1)),
                                   gb | (up << 16), __ATOMIC_RELAXED, __HIP_MEMORY_SCOPE_AGENT);
            float sq = g * g;
            #pragma unroll
            for (int off = 32; off; off >>= 1) sq += __shfl_xor(sq, off, 64);
            if (lane == 0) gsum[wv >> 1] = sq;
        }
        __syncthreads();   // ghist stores of all waves drained here
        if (tid == 0) {
            float tot = gsum[0] + gsum[1] + gsum[2] + gsum[3];
            __hip_atomic_store(msum + ((t & 1) * 16 + b) * 16 + j, tot,
                               __ATOMIC_RELAXED, __HIP_MEMORY_SCOPE_AGENT);
            asm volatile("s_waitcnt vmcnt(0)" ::: "memory");
            __hip_atomic_store(bflag + w * 32, (unsigned)(t + 1),
                               __ATOMIC_RELAXED, __HIP_MEMORY_SCOPE_AGENT);
        }
    }

    // ======== post-loop: fused out-projection (all 128 wgs) ========
    if (tid < 128) {
        const unsigned* fp = bflag + tid * 32;
        while (__hip_atomic_load(fp, __ATOMIC_RELAXED, __HIP_MEMORY_SCOPE_AGENT) < 512u) {}
    } else if (tid == 128) {
        while (__hip_atomic_load(sflag, __ATOMIC_RELAXED, __HIP_MEMORY_SCOPE_AGENT) < 1u) {}
    }
    __syncthreads();
    {
        const int vb = w * 2 + (tid >> 8);    // virtual 256-thread block: 0..255
        const int vt = tid & 255;
        const int vwv = vt >> 6, vlane = vt & 63;
        const int vcolr = vlane & 15, vq = vlane >> 4;   // vcolr = batch row of A
        for (int it = 0; it < 8; ++it) {
            const int idx = vb * 8 + it;       // 0..2047 = (t, n-block)
            const int tt = idx >> 2;
            const int n0 = (idx & 3) * 256 + vwv * 64;
            const long ab = (long)(tt + 1) * 8192 + vcolr * 512 + vq * 2;
            const short* bp = wall + ((long)(2336 + n0 + vcolr) * KD + vq * 8);
            floatx4 acc0 = {0.f,0.f,0.f,0.f}, acc1 = {0.f,0.f,0.f,0.f};
            floatx4 acc2 = {0.f,0.f,0.f,0.f}, acc3 = {0.f,0.f,0.f,0.f};
            #pragma unroll 4
            for (int kb = 0; kb < 64; ++kb) {
                unsigned long long a0 = __hip_atomic_load(gq + ab + kb * 8,
                                        __ATOMIC_RELAXED, __HIP_MEMORY_SCOPE_AGENT);
                unsigned long long a1 = __hip_atomic_load(gq + ab + kb * 8 + 1,
                                        __ATOMIC_RELAXED, __HIP_MEMORY_SCOPE_AGENT);
                union { unsigned long long u[2]; short8 s8; } af;
                af.u[0] = a0; af.u[1] = a1;
                const short* bk = bp + kb * 32;
                acc0 = __builtin_amdgcn_mfma_f32_16x16x32_bf16(af.s8, *(const short8*)(bk),           acc0, 0, 0, 0);
                acc1 = __builtin_amdgcn_mfma_f32_16x16x32_bf16(af.s8, *(const short8*)(bk + 16 * KD), acc1, 0, 0, 0);
                acc2 = __builtin_amdgcn_mfma_f32_16x16x32_bf16(af.s8, *(const short8*)(bk + 32 * KD), acc2, 0, 0, 0);
                acc3 = __builtin_amdgcn_mfma_f32_16x16x32_bf16(af.s8, *(const short8*)(bk + 48 * KD), acc3, 0, 0, 0);
            }
            #pragma unroll
            for (int r = 0; r < 4; ++r) {
                const int bb = vq * 4 + r;     // batch
                float sc = __hip_atomic_load(scale_hist + bb * LQ + tt,
                                             __ATOMIC_RELAXED, __HIP_MEMORY_SCOPE_AGENT);
                float* op = out + ((long)bb * LQ + tt) * DM + n0 + vcolr;
                op[0]  = acc0[r] * sc;
                op[16] = acc1[r] * sc;
                op[32] = acc2[r] * sc;
                op[48] = acc3[r] * sc;
            }
        }
    }
}

extern "C" void kernel_launch(void* const* d_in, const int* in_sizes, int n_in,
                              void* d_out, int out_size, void* d_ws, size_t ws_size,
                              hipStream_t stream) {
    const float* u       = (const float*)d_in[0];
    const float* W_in    = (const float*)d_in[1];
    const float* conv_w  = (const float*)d_in[2];
    const float* conv_b  = (const float*)d_in[3];
    const float* W_rxbc  = (const float*)d_in[4];
    const float* W_rdt   = (const float*)d_in[5];
    const float* dt_bias = (const float*)d_in[6];
    const float* A_log   = (const float*)d_in[7];
    const float* D_param = (const float*)d_in[8];
    const float* norm_w  = (const float*)d_in[9];
    const float* W_out   = (const float*)d_in[10];
    float* out = (float*)d_out;

    char* ws = (char*)d_ws;
    size_t off = 0;
    auto alloc = [&](size_t bytes) -> void* {
        void* p = ws + off; off += (bytes + 255) & ~(size_t)255; return p;
    };
    float* zx            = (float*)alloc((size_t)BQ * LQ * DPROJ * 4);        // 143.7 MB
    unsigned short* u_bf = (unsigned short*)alloc((size_t)BQ * LQ * DM * 2);  // reused as wall
    unsigned short* w_bf = (unsigned short*)alloc((size_t)DPROJ * DM * 2);
    unsigned short* gh   = (unsigned short*)alloc((size_t)(LQ + 1) * BQ * KD * 2);  // 33.6 MB
    float* msum          = (float*)alloc(512 * 4);
    float* raw           = (float*)alloc(2 * (size_t)BQ * RAWC * 4);
    float* scale_hist    = (float*)alloc((size_t)BQ * LQ * 4);
    unsigned* bar        = (unsigned*)alloc(12288 * 4);

    { int n = BQ * LQ * DM; cvt_bf16_kernel<<<(n + 255) / 256, 256, 0, stream>>>(u, u_bf, n); }
    { int n = DPROJ * DM;   cvt_bf16_kernel<<<(n + 255) / 256, 256, 0, stream>>>(W_in, w_bf, n); }
    gemm_inproj_kernel<<<dim3(BQ * LQ / 128, DPROJ / 32), 256, 0, stream>>>(
        (const short*)u_bf, (const short*)w_bf, zx);
    unsigned short* wall = u_bf;   // dead after GEMM; reuse for packed scan weights
    { long n = 3360L * KD;
      pack_weights_kernel<<<(int)((n + 255) / 256), 256, 0, stream>>>(W_rxbc, W_rdt, W_out, wall); }
    setup_zero_kernel<<<64, 256, 0, stream>>>((unsigned*)gh, msum, bar);

    void* args[] = { &zx, &raw, &gh, &msum, &bar, &wall, &scale_hist,
                     &dt_bias, &A_log, &D_param, &norm_w, &conv_w, &conv_b, &out };
    hipLaunchCooperativeKernel((void*)scan_kernel, dim3(NWG), dim3(NTHR), args, 0, stream);
}